// Round 3
// baseline (329.012 us; speedup 1.0000x reference)
//
#include <hip/hip_runtime.h>

#define RR 4
#define NS 17
#define BB 4
#define CC 128
#define HH 96
#define WW 160
#define HWSZ (HH * WW)
#define OUTN (BB * NS * HWSZ)    // 1,044,480 output floats

// Block: 32 (w) x 8 (h); each thread owns ONE pixel.
// Pixel tile: 8 rows x 32 cols. LDS tgt tile: 16 x 40 (halo R=4 each side),
// vectorized over 4 consecutive channels (float4), double-buffered, write-late.
#define TW 32
#define HTILE 8
#define TROWS (HTILE + 2 * RR)   // 16
#define TCOLS (TW + 2 * RR)      // 40
#define TILE_E (TROWS * TCOLS)   // 640 float4 = 10240 B per buffer
#define CCHUNK 32                // channels per block
#define NCHUNK (CC / CCHUNK)     // 4 partials per output
#define CG 4                     // channels per group (float4)
#define NG (CCHUNK / CG)         // 8 groups per block
#define NSPX (WW / TW)           // 5
#define NSPY (HH / HTILE)        // 12
#define NSP (NSPX * NSPY)        // 60 spatial tiles
#define NWG (NSP * BB * NCHUNK)  // 960 workgroups
#define NXCD 8
#define WGPX (NWG / NXCD)        // 120 (exact)

#define FMA4(a, t) \
    (a) = fmaf(svx, (t).x, fmaf(svy, (t).y, fmaf(svz, (t).z, fmaf(svw, (t).w, (a)))))

template <bool ATOMIC>
__global__ __launch_bounds__(256, 4)
void cost_volume_kernel(const float* __restrict__ src,
                        const float* __restrict__ tgt,
                        float* __restrict__ dst) {
    __shared__ float4 tile[2][TILE_E];    // 20480 B

    const int x   = threadIdx.x;          // 0..31
    const int hg  = threadIdx.y;          // 0..7
    const int tid = hg * TW + x;          // 0..255

    // Round-1 swizzle (proven ~39us): each XCD gets a contiguous wg range;
    // halo re-reads of a (b,chunk) tgt slice stay in that XCD's L2.
    const int flat = blockIdx.x;                      // 0..959
    const int wg   = (flat & (NXCD - 1)) * WGPX + (flat >> 3);
    const int sp   = wg % NSP;                        // spatial tile (x-fastest)
    const int z    = wg / NSP;                        // 0..15
    const int wx   = sp % NSPX;
    const int wy   = sp / NSPX;

    const int w0 = wx * TW;
    const int h0 = wy * HTILE;
    const int b  = z & 3;
    const int ch = z >> 2;                // chunk index 0..3
    const int c0 = ch * CCHUNK;

    const int w = w0 + x;                 // always < WW
    const int h = h0 + hg;                // always < HH

    const float* tgt_b = tgt + (size_t)(b * CC + c0) * HWSZ;
    const float* src_p = src + (size_t)(b * CC + c0) * HWSZ + h * WW + w;

    // --- staging slots (invariant across channel groups) ---
    int  sOff[3];
    bool sVal[3];
#pragma unroll
    for (int k = 0; k < 3; ++k) {
        const int idx = tid + k * 256;
        const int r   = idx / TCOLS;
        const int col = idx - r * TCOLS;
        const int gr  = h0 - RR + r;
        const int gc  = w0 - RR + col;
        sVal[k] = (idx < TILE_E) && gr >= 0 && gr < HH && gc >= 0 && gc < WW;
        sOff[k] = gr * WW + gc;
    }

    float4 pre[3];                        // tgt tile prefetch (3 f4/thread)
    float  svc[4];                        // src: current group
    float  svn[4];                        // src: next group (prefetch)

    auto fetch = [&](int g, float sv[4]) {
        const float* t = tgt_b + (size_t)(g * CG) * HWSZ;
#pragma unroll
        for (int k = 0; k < 3; ++k) {
            float4 v = make_float4(0.f, 0.f, 0.f, 0.f);
            if (sVal[k]) {
                const float* p = t + sOff[k];
                v.x = p[0];
                v.y = p[HWSZ];
                v.z = p[2 * HWSZ];
                v.w = p[3 * HWSZ];
            }
            pre[k] = v;
        }
        const float* s = src_p + (size_t)(g * CG) * HWSZ;
#pragma unroll
        for (int k = 0; k < 4; ++k) sv[k] = s[k * HWSZ];
    };

    auto store_tile = [&](int buf) {
        tile[buf][tid]       = pre[0];
        tile[buf][tid + 256] = pre[1];
        if (tid + 512 < TILE_E) tile[buf][tid + 512] = pre[2];
    };

    float acc[NS];
#pragma unroll
    for (int s = 0; s < NS; ++s) acc[s] = 0.f;

    // prologue: stage group 0 into buffer 0
    fetch(0, svc);
    store_tile(0);
    __syncthreads();

    const int base = (RR + hg) * TCOLS + (RR + x);

    for (int g = 0; g < NG; ++g) {   // rolled: cap live ranges / code bloat
        const int cur = g & 1;

        // issue next group's global loads early (latency hides under compute)
        if (g + 1 < NG) fetch(g + 1, svn);

        // compute: 17 ds_read_b128 + 68 FMAs (4 channels at once)
        {
            const float svx = svc[0], svy = svc[1], svz = svc[2], svw = svc[3];
            const float4* tb = tile[cur];
            float4 tc = tb[base];
            FMA4(acc[0], tc);
#pragma unroll
            for (int off = 1; off <= RR; ++off) {
                float4 tu = tb[base - off * TCOLS];
                float4 td = tb[base + off * TCOLS];
                float4 tl = tb[base - off];
                float4 tr = tb[base + off];
                FMA4(acc[4 * off - 3], tu);
                FMA4(acc[4 * off - 2], td);
                FMA4(acc[4 * off - 1], tl);
                FMA4(acc[4 * off    ], tr);
            }
        }

        // write-late: stage next group into the other buffer, ONE barrier/group.
        // (reads of tile[cur^1] ended before the barrier that closed iter g-1)
        if (g + 1 < NG) {
            store_tile(cur ^ 1);
#pragma unroll
            for (int k = 0; k < 4; ++k) svc[k] = svn[k];
            __syncthreads();
        }
    }

    // epilogue
    const size_t oidx = (((size_t)b * NS) * HH + h) * WW + w;
    if (ATOMIC) {
        float* op = dst + oidx;
#pragma unroll
        for (int s = 0; s < NS; ++s) atomicAdd(op + (size_t)s * HWSZ, acc[s]);
    } else {
        // private partial slice per chunk: plain coalesced stores, no sharing
        float* op = dst + (size_t)ch * OUTN + oidx;
#pragma unroll
        for (int s = 0; s < NS; ++s) op[(size_t)s * HWSZ] = acc[s];
    }
}

// out[i] = sum over 4 chunk partials; 21 MB traffic, float4 throughout.
__global__ __launch_bounds__(256)
void reduce_kernel(const float4* __restrict__ ws, float4* __restrict__ out) {
    const int i = blockIdx.x * 256 + threadIdx.x;
    const int n4 = OUTN / 4;              // 261,120
    if (i < n4) {
        float4 a = ws[i];
        float4 b = ws[i + n4];
        float4 c = ws[i + 2 * n4];
        float4 d = ws[i + 3 * n4];
        out[i] = make_float4(a.x + b.x + c.x + d.x,
                             a.y + b.y + c.y + d.y,
                             a.z + b.z + c.z + d.z,
                             a.w + b.w + c.w + d.w);
    }
}

extern "C" void kernel_launch(void* const* d_in, const int* in_sizes, int n_in,
                              void* d_out, int out_size, void* d_ws, size_t ws_size,
                              hipStream_t stream) {
    const float* src = (const float*)d_in[0];
    const float* tgt = (const float*)d_in[1];

    dim3 block(TW, 8, 1);                 // 256 threads
    const size_t need = (size_t)NCHUNK * OUTN * sizeof(float);  // 16.7 MB

    if (ws_size >= need) {
        // contention-free path: partials in workspace, then reduce. No memset.
        cost_volume_kernel<false><<<dim3(NWG, 1, 1), block, 0, stream>>>(
            src, tgt, (float*)d_ws);
        reduce_kernel<<<dim3(OUTN / 4 / 256, 1, 1), dim3(256, 1, 1), 0, stream>>>(
            (const float4*)d_ws, (float4*)d_out);
    } else {
        // fallback: atomic accumulation into zeroed output
        hipMemsetAsync(d_out, 0, (size_t)OUTN * sizeof(float), stream);
        cost_volume_kernel<true><<<dim3(NWG, 1, 1), block, 0, stream>>>(
            src, tgt, (float*)d_out);
    }
}

// Round 4
// 106.465 us; speedup vs baseline: 3.0903x; 3.0903x over previous
//
#include <hip/hip_runtime.h>

#define RR 4
#define NS 17
#define BB 4
#define CC 128
#define HH 96
#define WW 160
#define HWSZ (HH * WW)

// Block: 32 (w) x 8 (h); each thread owns ONE pixel.
// Pixel tile: 8 rows x 32 cols. LDS tgt tile: 16 x 40 (halo R=4 each side),
// vectorized over 4 consecutive channels (float4 per element).
// NOTE: this is the round-1 kernel, bit-exact (proven ~38us / 108us bench).
// Rounds 2-3 (write-late double-buffer) inflated HBM traffic 5-7x for reasons
// not yet isolated -> reverted. Do not reintroduce store-after-compute without
// a counter-verified mechanism for the round-2/3 traffic explosion.
#define TW 32
#define HTILE 8
#define TROWS (HTILE + 2 * RR)   // 16
#define TCOLS (TW + 2 * RR)      // 40
#define TILE_E (TROWS * TCOLS)   // 640 float4 elements = 10240 B
#define CCHUNK 32                // channels per block
#define NCHUNK (CC / CCHUNK)     // 4 (atomic-accumulated)
#define CG 4                     // channels per group (float4)
#define NG (CCHUNK / CG)         // 8 groups per block
#define NSPX (WW / TW)           // 5
#define NSPY (HH / HTILE)        // 12
#define NSP (NSPX * NSPY)        // 60 spatial tiles
#define NWG (NSP * BB * NCHUNK)  // 960 workgroups
#define NXCD 8
#define WGPX (NWG / NXCD)        // 120 (exact)

#define FMA4(a, t) \
    (a) = fmaf(svx, (t).x, fmaf(svy, (t).y, fmaf(svz, (t).z, fmaf(svw, (t).w, (a)))))

__global__ __launch_bounds__(256, 4)
void cost_volume_kernel(const float* __restrict__ src,
                        const float* __restrict__ tgt,
                        float* __restrict__ out) {
    __shared__ float4 tile[TILE_E];

    const int x   = threadIdx.x;          // 0..31
    const int hg  = threadIdx.y;          // 0..7
    const int tid = hg * TW + x;          // 0..255

    // XCD-aware bijective swizzle: HW round-robins consecutive dispatch ids
    // across 8 XCDs; remap so each XCD gets a contiguous work range
    // (spatial-major -> halo re-reads hit the same XCD's L2).
    // Also places all 4 channel-chunks of a given output on ONE XCD
    // (flat ids differing by 120 -> same XCD), so the atomicAdd lines
    // stay resident in a single L2 (round-0 counter proof: WRITE_SIZE
    // was exactly 4 B/atomic).
    const int flat = blockIdx.x;                      // dispatch id, 0..959
    const int wg   = (flat & (NXCD - 1)) * WGPX + (flat >> 3);
    const int sp   = wg % NSP;                        // spatial tile (x-fastest)
    const int z    = wg / NSP;                        // b*? + channel chunk
    const int wx   = sp % NSPX;
    const int wy   = sp / NSPX;

    const int w0 = wx * TW;
    const int h0 = wy * HTILE;
    const int b  = z & 3;
    const int c0 = (z >> 2) * CCHUNK;

    const int w = w0 + x;                 // always < WW
    const int h = h0 + hg;                // always < HH

    const float* tgt_b = tgt + (size_t)(b * CC + c0) * HWSZ;
    const float* src_p = src + (size_t)(b * CC + c0) * HWSZ + h * WW + w;

    // --- precompute staging slots (invariant across channel groups) ---
    int  sOff[3];
    bool sVal[3];
#pragma unroll
    for (int k = 0; k < 3; ++k) {
        const int idx = tid + k * 256;
        const int r   = idx / TCOLS;
        const int col = idx - r * TCOLS;
        const int gr  = h0 - RR + r;
        const int gc  = w0 - RR + col;
        sVal[k] = (idx < TILE_E) && gr >= 0 && gr < HH && gc >= 0 && gc < WW;
        sOff[k] = gr * WW + gc;
    }

    float4 pre[3];                        // tgt tile prefetch (3 f4/thread)
    float  sv4[4];                        // src prefetch (4 channels)

    auto fetch = [&](int g) {
        const float* t = tgt_b + (size_t)(g * CG) * HWSZ;
#pragma unroll
        for (int k = 0; k < 3; ++k) {
            float4 v = make_float4(0.f, 0.f, 0.f, 0.f);
            if (sVal[k]) {
                const float* p = t + sOff[k];
                v.x = p[0];
                v.y = p[HWSZ];
                v.z = p[2 * HWSZ];
                v.w = p[3 * HWSZ];
            }
            pre[k] = v;
        }
        const float* s = src_p + (size_t)(g * CG) * HWSZ;
#pragma unroll
        for (int k = 0; k < 4; ++k) sv4[k] = s[k * HWSZ];
    };

    float acc[NS];
#pragma unroll
    for (int s = 0; s < NS; ++s) acc[s] = 0.f;

    fetch(0);
    const int base = (RR + hg) * TCOLS + (RR + x);

    for (int g = 0; g < NG; ++g) {
        // write staged regs to LDS (b128 writes, conflict-balanced)
        tile[tid]       = pre[0];
        tile[tid + 256] = pre[1];
        if (tid + 512 < TILE_E) tile[tid + 512] = pre[2];
        const float svx = sv4[0], svy = sv4[1], svz = sv4[2], svw = sv4[3];
        __syncthreads();

        // prefetch next group while computing this one
        if (g + 1 < NG) fetch(g + 1);

        // compute: 17 ds_read_b128 + 68 FMAs (4 channels at once)
        {
            float4 tc = tile[base];
            FMA4(acc[0], tc);
#pragma unroll
            for (int off = 1; off <= RR; ++off) {
                float4 tu = tile[base - off * TCOLS];
                float4 td = tile[base + off * TCOLS];
                float4 tl = tile[base - off];
                float4 tr = tile[base + off];
                FMA4(acc[4 * off - 3], tu);
                FMA4(acc[4 * off - 2], td);
                FMA4(acc[4 * off - 1], tl);
                FMA4(acc[4 * off    ], tr);
            }
        }
        __syncthreads();
    }

    // epilogue: atomic accumulate (4 channel-chunks race per output)
    float* op = out + (((size_t)b * NS) * HH + h) * WW + w;
#pragma unroll
    for (int s = 0; s < NS; ++s) {
        atomicAdd(op + (size_t)s * HWSZ, acc[s]);
    }
}

extern "C" void kernel_launch(void* const* d_in, const int* in_sizes, int n_in,
                              void* d_out, int out_size, void* d_ws, size_t ws_size,
                              hipStream_t stream) {
    const float* src = (const float*)d_in[0];
    const float* tgt = (const float*)d_in[1];
    float* out = (float*)d_out;

    // d_out is poisoned before every launch; we accumulate atomically -> zero it
    hipMemsetAsync(out, 0, (size_t)out_size * sizeof(float), stream);

    dim3 block(TW, 8, 1);      // 256 threads
    dim3 grid(NWG, 1, 1);      // 960 blocks
    cost_volume_kernel<<<grid, block, 0, stream>>>(src, tgt, out);
}